// Round 1
// baseline (2412.249 us; speedup 1.0000x reference)
//
#include <hip/hip_runtime.h>
#include <stdint.h>

#define T_SEQ 2048

typedef __attribute__((ext_vector_type(8))) short short8;
typedef __attribute__((ext_vector_type(4))) float f32x4;

__device__ __forceinline__ unsigned short f2bf(float f){
  unsigned int u = __float_as_uint(f);
  unsigned int r = u + 0x7fffu + ((u >> 16) & 1u);
  return (unsigned short)(r >> 16);
}
__device__ __forceinline__ float bf2f(unsigned short h){
  return __uint_as_float(((unsigned int)h) << 16);
}
__device__ __forceinline__ float sig_(float x){
  float e = __builtin_amdgcn_exp2f(-1.44269504089f * x);
  return __builtin_amdgcn_rcpf(1.0f + e);
}
__device__ __forceinline__ float tanh_(float x){
  float e = __builtin_amdgcn_exp2f(2.88539008178f * x);
  return 1.0f - 2.0f * __builtin_amdgcn_rcpf(1.0f + e);
}
// Hamilton block value W[qr*64+kr][qc*192+nc]; comp = qr^qc, sign mask 0x5390
__device__ __forceinline__ float ham_val(int qr, int qc, int kr, int nc,
    const float* wr, const float* wi, const float* wj, const float* wk){
  int cc = qr ^ qc;
  const float* w = (cc==0)?wr:(cc==1)?wi:(cc==2)?wj:wk;
  float v = w[kr*192 + nc];
  if ((0x5390u >> (qr*4+qc)) & 1u) v = -v;
  return v;
}

// Build B'^T for the input GEMM: BT[c][k'], c = permuted column, k' in [0,768):
// k'<256 -> hi(W_ih), k' in [256,512) -> lo(W_ih), k'>=512 -> hi(W_ih)
__global__ __launch_bounds__(256) void k_prep_bt(const float* __restrict__ wr,
    const float* __restrict__ wi, const float* __restrict__ wj,
    const float* __restrict__ wk, unsigned short* __restrict__ BT){
  int idx = blockIdx.x*256 + threadIdx.x;       // 768*768
  int c = idx / 768, kp = idx - c*768;
  int kk = kp & 255, piece = kp >> 8;
  int qr = kk >> 6, kr = kk & 63;
  int e = (c/48)*16 + (c & 15);
  int g = (c % 48) >> 4;
  int qc = e >> 6;
  int nc = g*64 + (e & 63);
  float v = ham_val(qr, qc, kr, nc, wr, wi, wj, wk);
  unsigned short hi = f2bf(v);
  unsigned short o = (piece == 1) ? f2bf(v - bf2f(hi)) : hi;
  BT[(size_t)c*768 + kp] = o;
}

// Pre-swizzled W_hh B-fragments: [wv][p][g][kt][lane] -> 8 bf16 (16B) each
__global__ __launch_bounds__(256) void k_prep_whh(const float* __restrict__ wr,
    const float* __restrict__ wi, const float* __restrict__ wj,
    const float* __restrict__ wk, unsigned short* __restrict__ WF){
  int idx = blockIdx.x*256 + threadIdx.x;       // 24576
  int lane = idx & 63;
  int kt = (idx >> 6) & 7;
  int t3 = idx >> 9;
  int g = t3 % 3;
  int t4 = t3 / 3;
  int p = t4 & 1, wv = t4 >> 1;
  int u = lane & 15, quad = lane >> 4;
  int e = (wv*2 + p)*16 + u;                    // h-element index
  int qc = e >> 6;
  int nc = g*64 + (e & 63);
  short8 o;
  #pragma unroll
  for (int j = 0; j < 8; j++){
    int k = kt*32 + quad*8 + j;                 // B[k][n]: k = quad*8+j within tile
    int qr = k >> 6, kr = k & 63;
    o[j] = (short)f2bf(ham_val(qr, qc, kr, nc, wr, wi, wj, wk));
  }
  *(short8*)(WF + (size_t)idx*8) = o;
}

__global__ __launch_bounds__(256) void k_prep_bias(const float* __restrict__ bih,
    const float* __restrict__ bhh, float* __restrict__ bias){
  int c = blockIdx.x*256 + threadIdx.x;         // 768
  int e = (c/48)*16 + (c & 15);
  int g = (c % 48) >> 4;
  int n = (e >> 6)*192 + g*64 + (e & 63);
  bias[c] = bih[n] + bhh[n];
}

// gi = [x_hi x_hi x_lo] @ [W_hi; W_lo; W_hi] + (b_ih+b_hh), columns permuted.
// 128x128 tile, BK=64, 12 K-chunks. XOR-swizzled LDS (chunk ^= row&7).
__global__ __launch_bounds__(256) void k_gemm_gi(const float* __restrict__ x,
    const unsigned short* __restrict__ BT, const float* __restrict__ bias,
    float* __restrict__ gi){
  __shared__ unsigned short As[128*64];
  __shared__ unsigned short Bs[128*64];
  int tid = threadIdx.x;
  int mb = blockIdx.x / 6, nb = blockIdx.x - mb*6;   // nb fastest: A-slab L2 reuse
  int lane = tid & 63, wid = tid >> 6;
  int quad = lane >> 4, u = lane & 15;
  int wvm = wid >> 1, wvn = wid & 1;
  int srow = tid >> 3, cb = tid & 7;
  f32x4 acc[4][4] = {};
  for (int kc = 0; kc < 12; kc++){
    bool lop = (kc >= 8);
    int kbase = (kc & 3) * 64;
    #pragma unroll
    for (int rd = 0; rd < 4; rd++){
      int m = rd*32 + srow;
      int lc = cb ^ (m & 7);
      const float* xp = x + (size_t)(mb*128 + m)*256 + kbase + lc*8;
      float4 v0 = *(const float4*)xp;
      float4 v1 = *(const float4*)(xp + 4);
      float vv[8] = {v0.x, v0.y, v0.z, v0.w, v1.x, v1.y, v1.z, v1.w};
      short8 ov;
      #pragma unroll
      for (int q = 0; q < 8; q++){
        unsigned short hi = f2bf(vv[q]);
        ov[q] = (short)(lop ? f2bf(vv[q] - bf2f(hi)) : hi);
      }
      *(short8*)&As[m*64 + cb*8] = ov;
    }
    #pragma unroll
    for (int rd = 0; rd < 4; rd++){
      int c = rd*32 + srow;
      int lc = cb ^ (c & 7);
      const unsigned short* bp = BT + (size_t)(nb*128 + c)*768 + kc*64 + lc*8;
      *(short8*)&Bs[c*64 + cb*8] = *(const short8*)bp;
    }
    __syncthreads();
    #pragma unroll
    for (int ks = 0; ks < 2; ks++){
      short8 af[4], bf[4];
      #pragma unroll
      for (int i=0;i<4;i++){
        int row = 64*wvm + 16*i + u;
        af[i] = *(const short8*)&As[row*64 + ((4*ks+quad) ^ (u & 7))*8];
      }
      #pragma unroll
      for (int j=0;j<4;j++){
        int row = 64*wvn + 16*j + u;
        bf[j] = *(const short8*)&Bs[row*64 + ((4*ks+quad) ^ (u & 7))*8];
      }
      #pragma unroll
      for (int i=0;i<4;i++)
        #pragma unroll
        for (int j=0;j<4;j++)
          acc[i][j] = __builtin_amdgcn_mfma_f32_16x16x32_bf16(af[i], bf[j], acc[i][j], 0, 0, 0);
    }
    __syncthreads();
  }
  int cb2 = nb*128 + 64*wvn;
  #pragma unroll
  for (int j=0;j<4;j++){
    float bj = bias[cb2 + 16*j + u];
    #pragma unroll
    for (int i=0;i<4;i++){
      float* gp = gi + (size_t)(mb*128 + 64*wvm + 16*i + quad*4)*768 + cb2 + 16*j + u;
      #pragma unroll
      for (int r=0;r<4;r++)
        gp[(size_t)r*768] = acc[i][j][r] + bj;
    }
  }
}

// Recurrence: 1 workgroup = 1 batch chain. 8 waves; wave wv owns permuted
// columns [96wv, 96wv+96) = (32 h-elems x 3 gates) -> gating wave-local.
// W_hh bf16 persistent in 192 VGPRs/lane; h fp32 in lane regs; bf16 h copy
// double-buffered in LDS for the replicated-A MFMA; 1 barrier/step.
__global__ __launch_bounds__(512, 2) void k_rec(const float* __restrict__ gi,
    const short8* __restrict__ WF, const float* __restrict__ hx,
    float* __restrict__ out){
  __shared__ unsigned short hbuf[2][256];
  int tid = threadIdx.x;
  int b = blockIdx.x;
  int lane = tid & 63, wv = tid >> 6;
  int quad = lane >> 4, u = lane & 15;
  int p16 = quad & 1;
  short8 Bf[48];
  #pragma unroll
  for (int p=0;p<2;p++)
    #pragma unroll
    for (int g=0;g<3;g++)
      #pragma unroll
      for (int kt=0;kt<8;kt++)
        Bf[(p*3+g)*8+kt] = WF[(size_t)((((wv*2+p)*3+g)*8 + kt)*64 + lane)];
  int e = wv*32 + (lane & 31);
  float h = hx[b*256 + e];
  if (lane < 32) hbuf[0][e] = f2bf(h);
  int c0 = wv*96 + p16*48 + u;
  const float* gbase = gi + (size_t)b*768 + c0;
  float gc0 = gbase[0], gc1 = gbase[16], gc2 = gbase[32];
  float* outp = out + (size_t)b*256 + e;
  __syncthreads();
  for (int t = 0; t < T_SEQ; t++){
    int tn = (t+1 < T_SEQ) ? (t+1) : (T_SEQ-1);
    const float* gn = gbase + (size_t)tn * (64*768);
    float n0 = gn[0], n1 = gn[16], n2 = gn[32];   // prefetch gi[t+1]
    const unsigned short* hb = hbuf[t & 1];
    f32x4 acc[2][3] = {};
    #pragma unroll
    for (int kt = 0; kt < 8; kt++){
      short8 a = *(const short8*)&hb[kt*32 + quad*8];   // h replicated over M
      #pragma unroll
      for (int p=0;p<2;p++)
        #pragma unroll
        for (int g=0;g<3;g++)
          acc[p][g] = __builtin_amdgcn_mfma_f32_16x16x32_bf16(a, Bf[(p*3+g)*8+kt], acc[p][g], 0, 0, 0);
    }
    float rpre = p16 ? acc[1][0][0] : acc[0][0][0];
    float zpre = p16 ? acc[1][1][0] : acc[0][1][0];
    float npre = p16 ? acc[1][2][0] : acc[0][2][0];
    float r = sig_(gc0 + rpre);
    float z = sig_(gc1 + zpre);
    float nn = tanh_(gc2 + r * npre);
    h = nn + z * (h - nn);
    if (lane < 32){
      outp[(size_t)t * (64*256)] = h;
      hbuf[(t+1) & 1][e] = f2bf(h);
    }
    gc0 = n0; gc1 = n1; gc2 = n2;
    __syncthreads();
  }
  if (lane < 32) out[(size_t)T_SEQ*64*256 + b*256 + e] = h;
}

extern "C" void kernel_launch(void* const* d_in, const int* in_sizes, int n_in,
                              void* d_out, int out_size, void* d_ws, size_t ws_size,
                              hipStream_t stream){
  const float* x    = (const float*)d_in[0];
  const float* hx   = (const float*)d_in[1];
  const float* wihr = (const float*)d_in[2];
  const float* wihi = (const float*)d_in[3];
  const float* wihj = (const float*)d_in[4];
  const float* wihk = (const float*)d_in[5];
  const float* whhr = (const float*)d_in[6];
  const float* whhi = (const float*)d_in[7];
  const float* whhj = (const float*)d_in[8];
  const float* whhk = (const float*)d_in[9];
  const float* bih  = (const float*)d_in[10];
  const float* bhh  = (const float*)d_in[11];
  char* ws = (char*)d_ws;
  float* gi          = (float*)ws;                            // 402,653,184 B
  unsigned short* BT = (unsigned short*)(ws + 402653184ull);  //   1,179,648 B
  unsigned short* WF = (unsigned short*)(ws + 403832832ull);  //     393,216 B
  float* bias        = (float*)(ws + 404226048ull);           //       3,072 B
  k_prep_bt  <<<dim3(2304), dim3(256), 0, stream>>>(wihr, wihi, wihj, wihk, BT);
  k_prep_whh <<<dim3(96),   dim3(256), 0, stream>>>(whhr, whhi, whhj, whhk, WF);
  k_prep_bias<<<dim3(3),    dim3(256), 0, stream>>>(bih, bhh, bias);
  k_gemm_gi  <<<dim3(6144), dim3(256), 0, stream>>>(x, BT, bias, gi);
  k_rec      <<<dim3(64),   dim3(512), 0, stream>>>(gi, (const short8*)WF, hx, (float*)d_out);
}